// Round 1
// baseline (181.358 us; speedup 1.0000x reference)
//
#include <hip/hip_runtime.h>

#define NHEAD 4
#define NNODE 4096
#define DIM 256
#define ROWS 64
#define CT 64
#define NTH 512
#define NEGV (-9e15f)

typedef float        f32x4  __attribute__((ext_vector_type(4)));
typedef int          i32x4  __attribute__((ext_vector_type(4)));
typedef unsigned int u32x2  __attribute__((ext_vector_type(2)));
typedef unsigned int u32x4  __attribute__((ext_vector_type(4)));
typedef short        bf16x8 __attribute__((ext_vector_type(8)));
typedef float        f32x16 __attribute__((ext_vector_type(16)));

__device__ __forceinline__ unsigned int f2bf(float f) {
  unsigned int u = __float_as_uint(f);
  u += 0x7fffu + ((u >> 16) & 1u);   // round-nearest-even to bf16
  return u >> 16;
}

// Fused: score=lrelu(att), adjacency mask, online row-softmax, P@X via bf16 MFMA.
// Per WG: head h, 64 output rows; stream 64-col tiles of att/adj; stage P and
// transposed-X tiles in swizzled LDS; 8 waves each own a 32-wide D slice.
__global__ __launch_bounds__(NTH, 4) void gat_fused(
    const float* __restrict__ xg, const int* __restrict__ adj,
    const float* __restrict__ att, float* __restrict__ outg) {
  __shared__ __align__(16) unsigned short p_lds[ROWS * CT];   // 8 KB
  __shared__ __align__(16) unsigned short xT_lds[DIM * CT];   // 32 KB
  __shared__ __align__(16) float fac_lds[ROWS];
  __shared__ __align__(16) float l_lds[ROWS];

  const int t = threadIdx.x;
  const int lane = t & 63;

  // XCD-aware decode: block i -> XCD i%8 (round-robin dispatch); give each XCD
  // one half of one head so x[h] (4 MiB) can live in that XCD's L2.
  const int flat = blockIdx.x;              // 0..255
  const int xcd  = flat & 7;
  const int h    = xcd >> 1;                // 0..3
  const int rb   = ((xcd & 1) << 5) | (flat >> 3);  // 0..63
  const int r0   = rb * ROWS;

  // score-phase mapping: thread -> (row, 8 cols)
  const int srow = t >> 3;                  // 0..63
  const int sm0  = (t & 7) << 3;            // 0..56
  const float* attb = att + ((size_t)h * NNODE + (r0 + srow)) * NNODE + sm0;
  const int*   adjb = adj + (size_t)(r0 + srow) * NNODE + sm0;

  // x-stage mapping: thread -> 4 m-rows x 4 d-cols blocks
  const int xm0 = (t >> 5) << 2;            // 0..60
  const int xd0 = (t & 31) << 2;            // 0..124
  const float* xb_h = xg + (size_t)h * NNODE * DIM;

  // mfma mapping: wave -> 32-wide D slice, all 64 rows
  const int wv   = t >> 6;
  const int d0   = wv << 5;
  const int lhi  = lane >> 5;
  const int lcol = lane & 31;

  f32x16 acc0 = {0.f};
  f32x16 acc1 = {0.f};
  float m_run = -__builtin_inff();
  float l_run = 0.f;

  for (int it = 0; it < NNODE / CT; ++it) {
    const int c0 = it * CT;
    // ---------------- scores + online softmax ----------------
    {
      const f32x4 a0 = __builtin_nontemporal_load((const f32x4*)(attb + c0));
      const f32x4 a1 = __builtin_nontemporal_load((const f32x4*)(attb + c0) + 1);
      const i32x4 j0 = *((const i32x4*)(adjb + c0));
      const i32x4 j1 = *((const i32x4*)(adjb + c0) + 1);
      float sv[8];
      int   av[8];
#pragma unroll
      for (int k = 0; k < 4; ++k) { sv[k] = a0[k]; sv[4 + k] = a1[k]; av[k] = j0[k]; av[4 + k] = j1[k]; }
#pragma unroll
      for (int k = 0; k < 8; ++k) {
        float s = sv[k];
        s = s > 0.f ? s : 0.2f * s;            // leaky_relu(0.2)
        sv[k] = (av[k] > 0) ? s : NEGV;        // adjacency mask
      }
      float tmax = sv[0];
#pragma unroll
      for (int k = 1; k < 8; ++k) tmax = fmaxf(tmax, sv[k]);
      tmax = fmaxf(tmax, __shfl_xor(tmax, 1));
      tmax = fmaxf(tmax, __shfl_xor(tmax, 2));
      tmax = fmaxf(tmax, __shfl_xor(tmax, 4));
      const float m_new = fmaxf(m_run, tmax);
      float ps = 0.f;
#pragma unroll
      for (int k = 0; k < 8; ++k) { sv[k] = __expf(sv[k] - m_new); ps += sv[k]; }
      ps += __shfl_xor(ps, 1);
      ps += __shfl_xor(ps, 2);
      ps += __shfl_xor(ps, 4);
      const float fac = __expf(m_run - m_new); // first iter: exp(-inf)=0
      l_run = l_run * fac + ps;
      m_run = m_new;
      if ((t & 7) == 0) fac_lds[srow] = fac;
      u32x4 pk;
      pk[0] = f2bf(sv[0]) | (f2bf(sv[1]) << 16);
      pk[1] = f2bf(sv[2]) | (f2bf(sv[3]) << 16);
      pk[2] = f2bf(sv[4]) | (f2bf(sv[5]) << 16);
      pk[3] = f2bf(sv[6]) | (f2bf(sv[7]) << 16);
      // swizzle: elem(m) = m ^ ((row&7)<<3)  (16B-granular XOR -> CF b128 reads)
      *(u32x4*)&p_lds[srow * CT + (sm0 ^ ((srow & 7) << 3))] = pk;
    }
    // ---------------- stage x tile: [m][d] -> xT_lds[d][m] bf16 ----------------
    {
      const float* xb = xb_h + (size_t)(c0 + xm0) * DIM;
#pragma unroll
      for (int hh2 = 0; hh2 < 2; ++hh2) {
        const int dbase = xd0 + hh2 * 128;
        const f32x4 r0v = *(const f32x4*)(xb + dbase);
        const f32x4 r1v = *(const f32x4*)(xb + DIM + dbase);
        const f32x4 r2v = *(const f32x4*)(xb + 2 * DIM + dbase);
        const f32x4 r3v = *(const f32x4*)(xb + 3 * DIM + dbase);
#pragma unroll
        for (int j = 0; j < 4; ++j) {          // in-register 4x4 transpose
          const int d = dbase + j;
          u32x2 wds;
          wds[0] = f2bf(r0v[j]) | (f2bf(r1v[j]) << 16);
          wds[1] = f2bf(r2v[j]) | (f2bf(r3v[j]) << 16);
          // swizzle s=(d>>2)&7: CF for both these b64 writes and b128 B-frag reads
          *(u32x2*)&xT_lds[d * CT + (xm0 ^ (((d >> 2) & 7) << 3))] = wds;
        }
      }
    }
    __syncthreads();
    // ---------------- rescale + MFMA ----------------
    {
#pragma unroll
      for (int q = 0; q < 4; ++q) {
        const f32x4 fa = *(const f32x4*)&fac_lds[q * 8 + lhi * 4];
        const f32x4 fb = *(const f32x4*)&fac_lds[32 + q * 8 + lhi * 4];
#pragma unroll
        for (int i = 0; i < 4; ++i) { acc0[q * 4 + i] *= fa[i]; acc1[q * 4 + i] *= fb[i]; }
      }
#pragma unroll
      for (int ks = 0; ks < 4; ++ks) {
        const int mk = ks * 16 + lhi * 8;      // A/B: k = 8*(lane>>5)+j
        const bf16x8 afA = *(const bf16x8*)&p_lds[lcol * CT + (mk ^ ((lcol & 7) << 3))];
        const bf16x8 afB = *(const bf16x8*)&p_lds[(32 + lcol) * CT + (mk ^ ((lcol & 7) << 3))];
        const int dd = d0 + lcol;
        const bf16x8 bfr = *(const bf16x8*)&xT_lds[dd * CT + (mk ^ (((dd >> 2) & 7) << 3))];
        acc0 = __builtin_amdgcn_mfma_f32_32x32x16_bf16(afA, bfr, acc0, 0, 0, 0);
        acc1 = __builtin_amdgcn_mfma_f32_32x32x16_bf16(afB, bfr, acc1, 0, 0, 0);
      }
    }
    __syncthreads();
  }
  // ---------------- epilogue: divide by softmax denom, store ----------------
  if ((t & 7) == 0) l_lds[srow] = l_run;
  __syncthreads();
  float* outb = outg + (size_t)h * NNODE * DIM + (size_t)r0 * DIM + d0 + lcol;
#pragma unroll
  for (int q = 0; q < 4; ++q) {
    const f32x4 la = *(const f32x4*)&l_lds[q * 8 + lhi * 4];
    const f32x4 lb = *(const f32x4*)&l_lds[32 + q * 8 + lhi * 4];
    const int rbase = q * 8 + lhi * 4;   // C/D row = (reg&3)+8*(reg>>2)+4*(lane>>5)
#pragma unroll
    for (int i = 0; i < 4; ++i) {
      __builtin_nontemporal_store(acc0[q * 4 + i] / la[i], outb + (size_t)(rbase + i) * DIM);
      __builtin_nontemporal_store(acc1[q * 4 + i] / lb[i], outb + (size_t)(32 + rbase + i) * DIM);
    }
  }
}

extern "C" void kernel_launch(void* const* d_in, const int* in_sizes, int n_in,
                              void* d_out, int out_size, void* d_ws, size_t ws_size,
                              hipStream_t stream) {
  const float* xg  = (const float*)d_in[0];
  const int*   adj = (const int*)d_in[1];
  const float* att = (const float*)d_in[2];
  float*       outg = (float*)d_out;
  gat_fused<<<dim3(256), dim3(NTH), 0, stream>>>(xg, adj, att, outg);
}

// Round 2
// 136.057 us; speedup vs baseline: 1.3330x; 1.3330x over previous
//
#include <hip/hip_runtime.h>

#define NHEAD 4
#define NNODE 4096
#define DIM 256
#define ROWS 64
#define CT 64
#define NT (NNODE / CT)
#define NTH 1024
#define NEGV (-9e15f)

typedef float        f32x4  __attribute__((ext_vector_type(4)));
typedef int          i32x4  __attribute__((ext_vector_type(4)));
typedef unsigned int u32x2  __attribute__((ext_vector_type(2)));
typedef unsigned int u32x4  __attribute__((ext_vector_type(4)));
typedef short        bf16x8 __attribute__((ext_vector_type(8)));
typedef float        f32x16 __attribute__((ext_vector_type(16)));

__device__ __forceinline__ unsigned int f2bf(float f) {
  unsigned int u = __float_as_uint(f);
  u += 0x7fffu + ((u >> 16) & 1u);   // RNE to bf16
  return u >> 16;
}

// ---------- pre-pass 1: xT[h][d][n] = bf16(x[h][n][d])  (8 MB in ws) ----------
__global__ __launch_bounds__(256) void prep_xT(const float* __restrict__ xg,
                                               unsigned short* __restrict__ xT) {
  __shared__ unsigned short tile[64][72];   // pad 72: 144B rows, 16B-aligned
  const int b  = blockIdx.x;
  const int h  = b >> 8;
  const int nb = (b >> 2) & 63;
  const int db = b & 3;
  const int n0 = nb << 6, d0 = db << 6;
  const int t  = threadIdx.x;
  const int tr = t >> 4;
  const int tc = (t & 15) << 2;
#pragma unroll
  for (int r = 0; r < 64; r += 16) {
    const f32x4 v = *(const f32x4*)(xg + ((size_t)h * NNODE + n0 + tr + r) * DIM + d0 + tc);
#pragma unroll
    for (int j = 0; j < 4; ++j) tile[tc + j][tr + r] = (unsigned short)f2bf(v[j]);
  }
  __syncthreads();
  const int d = t >> 2, nc = (t & 3) << 4;
  const bf16x8 w0 = *(const bf16x8*)&tile[d][nc];
  const bf16x8 w1 = *(const bf16x8*)&tile[d][nc + 8];
  unsigned short* ob = xT + ((size_t)h * DIM + d0 + d) * NNODE + n0 + nc;
  *(bf16x8*)ob = w0;
  *(bf16x8*)(ob + 8) = w1;
}

// ---------- pre-pass 2: adjacency -> bitmask (2 MB in ws, L2-resident) ----------
__global__ __launch_bounds__(256) void prep_adj(const int* __restrict__ adj,
                                                unsigned int* __restrict__ bits) {
  const int row = blockIdx.x;
  const int t = threadIdx.x;
  const int lane = t & 63, wv = t >> 6;
#pragma unroll
  for (int rep = 0; rep < 16; ++rep) {
    const int c = (rep << 8) + t;
    const unsigned long long m = __ballot(adj[(size_t)row * NNODE + c] > 0);
    if (lane == 0) {
      bits[row * 128 + (rep << 3) + (wv << 1)]     = (unsigned int)m;
      bits[row * 128 + (rep << 3) + (wv << 1) + 1] = (unsigned int)(m >> 32);
    }
  }
}

// ---------- main: fused lrelu+mask+online-softmax+PV, pipelined ----------
// 16 waves/block, grid=256 (1 block/CU). Reg-prefetch next tile; dbuf LDS;
// ONE barrier per iteration (write buf^1 while others read buf is safe).
__global__ __launch_bounds__(NTH, 4) void gat_fused_v2(
    const unsigned short* __restrict__ xT, const unsigned int* __restrict__ abits,
    const float* __restrict__ att, float* __restrict__ outg) {
  __shared__ unsigned short p_lds[2][ROWS * CT];    // 16 KB
  __shared__ unsigned short xt_lds[2][DIM * CT];    // 64 KB
  __shared__ float fac_lds[2][ROWS];
  __shared__ float l_lds[ROWS];

  const int t = threadIdx.x;
  const int lane = t & 63;
  const int flat = blockIdx.x;
  const int xcd = flat & 7;                 // round-robin XCD dispatch
  const int h   = xcd >> 1;                 // x[h] pinned to an XCD pair's L2
  const int rb  = ((xcd & 1) << 5) | (flat >> 3);
  const int r0  = rb * ROWS;

  // score mapping: 16 threads per row, 4 cols each
  const int sr = t >> 4;
  const int c4 = (t & 15) << 2;
  const float* attb = att + ((size_t)h * NNODE + r0 + sr) * NNODE + c4;
  const unsigned int* ab = abits + (size_t)(r0 + sr) * 128 + ((t & 15) >> 3);
  const int bsh = (t & 7) << 2;

  // x-stage mapping: thread -> d row, 16-col chunk
  const int xd = t >> 2;
  const int xmc = (t & 3) << 4;
  const unsigned short* xb = xT + ((size_t)h * DIM + xd) * NNODE + xmc;

  // mfma mapping: wave -> (row half, 32-wide d slice)
  const int wv = t >> 6;
  const int mh = wv & 1;
  const int d0 = (wv >> 1) << 5;
  const int lhi = lane >> 5;
  const int lcol = lane & 31;

  f32x16 acc = {0.f};
  float m_run = -__builtin_inff();
  float l_run = 0.f;

  // prologue: tile 0 into regs
  f32x4 ca = __builtin_nontemporal_load((const f32x4*)attb);
  unsigned int cw = ab[0];
  bf16x8 cx0 = *(const bf16x8*)xb;
  bf16x8 cx1 = *(const bf16x8*)(xb + 8);

  int buf = 0;
  for (int it = 0; it < NT; ++it) {
    // ---- issue next-tile loads first (hide HBM latency under this iter) ----
    const int itn = (it + 1) & (NT - 1);
    const int c0n = itn * CT;
    const f32x4 na = __builtin_nontemporal_load((const f32x4*)(attb + c0n));
    const unsigned int nw = ab[itn << 1];
    const bf16x8 nx0 = *(const bf16x8*)(xb + c0n);
    const bf16x8 nx1 = *(const bf16x8*)(xb + c0n + 8);

    // ---- softmax on current regs ----
    float sv[4];
#pragma unroll
    for (int k = 0; k < 4; ++k) {
      float s = ca[k];
      s = s > 0.f ? s : 0.2f * s;                       // leaky_relu(0.2)
      sv[k] = ((cw >> (bsh + k)) & 1u) ? s : NEGV;      // adjacency mask
    }
    float tmax = fmaxf(fmaxf(sv[0], sv[1]), fmaxf(sv[2], sv[3]));
    tmax = fmaxf(tmax, __shfl_xor(tmax, 1));
    tmax = fmaxf(tmax, __shfl_xor(tmax, 2));
    tmax = fmaxf(tmax, __shfl_xor(tmax, 4));
    tmax = fmaxf(tmax, __shfl_xor(tmax, 8));
    const float m_new = fmaxf(m_run, tmax);
    float ps = 0.f;
#pragma unroll
    for (int k = 0; k < 4; ++k) { sv[k] = __expf(sv[k] - m_new); ps += sv[k]; }
    ps += __shfl_xor(ps, 1);
    ps += __shfl_xor(ps, 2);
    ps += __shfl_xor(ps, 4);
    ps += __shfl_xor(ps, 8);
    const float fac = __expf(m_run - m_new);   // iter 0: exp(-inf)=0
    l_run = l_run * fac + ps;
    m_run = m_new;
    if ((t & 15) == 0) fac_lds[buf][sr] = fac;
    u32x2 pk;
    pk[0] = f2bf(sv[0]) | (f2bf(sv[1]) << 16);
    pk[1] = f2bf(sv[2]) | (f2bf(sv[3]) << 16);
    // 16B-block XOR swizzle keyed by row
    *(u32x2*)&p_lds[buf][sr * CT + (c4 ^ ((sr & 7) << 3))] = pk;
    // stage pre-transposed x tile (bf16, straight copy)
    *(bf16x8*)&xt_lds[buf][xd * CT + (xmc ^ ((xd & 7) << 3))] = cx0;
    *(bf16x8*)&xt_lds[buf][xd * CT + ((xmc + 8) ^ ((xd & 7) << 3))] = cx1;

    __syncthreads();   // the only barrier per iteration

    // ---- rescale + MFMA from LDS[buf] ----
#pragma unroll
    for (int q = 0; q < 4; ++q) {
      const f32x4 fa = *(const f32x4*)&fac_lds[buf][mh * 32 + q * 8 + lhi * 4];
#pragma unroll
      for (int i = 0; i < 4; ++i) acc[q * 4 + i] *= fa[i];
    }
    const int arow = mh * 32 + lcol;
    const int dd = d0 + lcol;
#pragma unroll
    for (int ks = 0; ks < 4; ++ks) {
      const int mk = ks * 16 + lhi * 8;
      const bf16x8 A = *(const bf16x8*)&p_lds[buf][arow * CT + (mk ^ ((arow & 7) << 3))];
      const bf16x8 B = *(const bf16x8*)&xt_lds[buf][dd * CT + (mk ^ ((dd & 7) << 3))];
      acc = __builtin_amdgcn_mfma_f32_32x32x16_bf16(A, B, acc, 0, 0, 0);
    }

    ca = na; cw = nw; cx0 = nx0; cx1 = nx1;
    buf ^= 1;
  }

  // ---- epilogue ----
  if ((t & 15) == 0) l_lds[sr] = l_run;
  __syncthreads();
  float* outb = outg + ((size_t)h * NNODE + r0 + mh * 32) * DIM + d0 + lcol;
#pragma unroll
  for (int q = 0; q < 4; ++q) {
    const f32x4 lv = *(const f32x4*)&l_lds[mh * 32 + q * 8 + lhi * 4];
    const int rbase = q * 8 + lhi * 4;   // C/D row = (reg&3)+8*(reg>>2)+4*(lane>>5)
#pragma unroll
    for (int i = 0; i < 4; ++i)
      __builtin_nontemporal_store(acc[q * 4 + i] / lv[i], outb + (size_t)(rbase + i) * DIM);
  }
}

// ---------- R1 kernel kept as fallback when ws is too small ----------
__global__ __launch_bounds__(512, 4) void gat_fused(
    const float* __restrict__ xg, const int* __restrict__ adj,
    const float* __restrict__ att, float* __restrict__ outg) {
  __shared__ __align__(16) unsigned short p_lds[ROWS * CT];
  __shared__ __align__(16) unsigned short xT_lds[DIM * CT];
  __shared__ __align__(16) float fac_lds[ROWS];
  __shared__ __align__(16) float l_lds[ROWS];
  const int t = threadIdx.x;
  const int lane = t & 63;
  const int flat = blockIdx.x;
  const int xcd  = flat & 7;
  const int h    = xcd >> 1;
  const int rb   = ((xcd & 1) << 5) | (flat >> 3);
  const int r0   = rb * ROWS;
  const int srow = t >> 3;
  const int sm0  = (t & 7) << 3;
  const float* attb = att + ((size_t)h * NNODE + (r0 + srow)) * NNODE + sm0;
  const int*   adjb = adj + (size_t)(r0 + srow) * NNODE + sm0;
  const int xm0 = (t >> 5) << 2;
  const int xd0 = (t & 31) << 2;
  const float* xb_h = xg + (size_t)h * NNODE * DIM;
  const int wv   = t >> 6;
  const int d0   = wv << 5;
  const int lhi  = lane >> 5;
  const int lcol = lane & 31;
  f32x16 acc0 = {0.f};
  f32x16 acc1 = {0.f};
  float m_run = -__builtin_inff();
  float l_run = 0.f;
  for (int it = 0; it < NNODE / CT; ++it) {
    const int c0 = it * CT;
    {
      const f32x4 a0 = __builtin_nontemporal_load((const f32x4*)(attb + c0));
      const f32x4 a1 = __builtin_nontemporal_load((const f32x4*)(attb + c0) + 1);
      const i32x4 j0 = *((const i32x4*)(adjb + c0));
      const i32x4 j1 = *((const i32x4*)(adjb + c0) + 1);
      float sv[8];
      int   av[8];
#pragma unroll
      for (int k = 0; k < 4; ++k) { sv[k] = a0[k]; sv[4 + k] = a1[k]; av[k] = j0[k]; av[4 + k] = j1[k]; }
#pragma unroll
      for (int k = 0; k < 8; ++k) {
        float s = sv[k];
        s = s > 0.f ? s : 0.2f * s;
        sv[k] = (av[k] > 0) ? s : NEGV;
      }
      float tmax = sv[0];
#pragma unroll
      for (int k = 1; k < 8; ++k) tmax = fmaxf(tmax, sv[k]);
      tmax = fmaxf(tmax, __shfl_xor(tmax, 1));
      tmax = fmaxf(tmax, __shfl_xor(tmax, 2));
      tmax = fmaxf(tmax, __shfl_xor(tmax, 4));
      const float m_new = fmaxf(m_run, tmax);
      float ps = 0.f;
#pragma unroll
      for (int k = 0; k < 8; ++k) { sv[k] = __expf(sv[k] - m_new); ps += sv[k]; }
      ps += __shfl_xor(ps, 1);
      ps += __shfl_xor(ps, 2);
      ps += __shfl_xor(ps, 4);
      const float fac = __expf(m_run - m_new);
      l_run = l_run * fac + ps;
      m_run = m_new;
      if ((t & 7) == 0) fac_lds[srow] = fac;
      u32x4 pk;
      pk[0] = f2bf(sv[0]) | (f2bf(sv[1]) << 16);
      pk[1] = f2bf(sv[2]) | (f2bf(sv[3]) << 16);
      pk[2] = f2bf(sv[4]) | (f2bf(sv[5]) << 16);
      pk[3] = f2bf(sv[6]) | (f2bf(sv[7]) << 16);
      *(u32x4*)&p_lds[srow * CT + (sm0 ^ ((srow & 7) << 3))] = pk;
    }
    {
      const float* xb = xb_h + (size_t)(c0 + xm0) * DIM;
#pragma unroll
      for (int hh2 = 0; hh2 < 2; ++hh2) {
        const int dbase = xd0 + hh2 * 128;
        const f32x4 r0v = *(const f32x4*)(xb + dbase);
        const f32x4 r1v = *(const f32x4*)(xb + DIM + dbase);
        const f32x4 r2v = *(const f32x4*)(xb + 2 * DIM + dbase);
        const f32x4 r3v = *(const f32x4*)(xb + 3 * DIM + dbase);
#pragma unroll
        for (int j = 0; j < 4; ++j) {
          const int d = dbase + j;
          u32x2 wds;
          wds[0] = f2bf(r0v[j]) | (f2bf(r1v[j]) << 16);
          wds[1] = f2bf(r2v[j]) | (f2bf(r3v[j]) << 16);
          *(u32x2*)&xT_lds[d * CT + (xm0 ^ (((d >> 2) & 7) << 3))] = wds;
        }
      }
    }
    __syncthreads();
    {
#pragma unroll
      for (int q = 0; q < 4; ++q) {
        const f32x4 fa = *(const f32x4*)&fac_lds[q * 8 + lhi * 4];
        const f32x4 fb = *(const f32x4*)&fac_lds[32 + q * 8 + lhi * 4];
#pragma unroll
        for (int i = 0; i < 4; ++i) { acc0[q * 4 + i] *= fa[i]; acc1[q * 4 + i] *= fb[i]; }
      }
#pragma unroll
      for (int ks = 0; ks < 4; ++ks) {
        const int mk = ks * 16 + lhi * 8;
        const bf16x8 afA = *(const bf16x8*)&p_lds[lcol * CT + (mk ^ ((lcol & 7) << 3))];
        const bf16x8 afB = *(const bf16x8*)&p_lds[(32 + lcol) * CT + (mk ^ ((lcol & 7) << 3))];
        const int dd = d0 + lcol;
        const bf16x8 bfr = *(const bf16x8*)&xT_lds[dd * CT + (mk ^ (((dd >> 2) & 7) << 3))];
        acc0 = __builtin_amdgcn_mfma_f32_32x32x16_bf16(afA, bfr, acc0, 0, 0, 0);
        acc1 = __builtin_amdgcn_mfma_f32_32x32x16_bf16(afB, bfr, acc1, 0, 0, 0);
      }
    }
    __syncthreads();
  }
  if ((t & 7) == 0) l_lds[srow] = l_run;
  __syncthreads();
  float* outb = outg + (size_t)h * NNODE * DIM + (size_t)r0 * DIM + d0 + lcol;
#pragma unroll
  for (int q = 0; q < 4; ++q) {
    const f32x4 la = *(const f32x4*)&l_lds[q * 8 + lhi * 4];
    const f32x4 lb = *(const f32x4*)&l_lds[32 + q * 8 + lhi * 4];
    const int rbase = q * 8 + lhi * 4;
#pragma unroll
    for (int i = 0; i < 4; ++i) {
      __builtin_nontemporal_store(acc0[q * 4 + i] / la[i], outb + (size_t)(rbase + i) * DIM);
      __builtin_nontemporal_store(acc1[q * 4 + i] / lb[i], outb + (size_t)(32 + rbase + i) * DIM);
    }
  }
}

extern "C" void kernel_launch(void* const* d_in, const int* in_sizes, int n_in,
                              void* d_out, int out_size, void* d_ws, size_t ws_size,
                              hipStream_t stream) {
  const float* xg  = (const float*)d_in[0];
  const int*   adj = (const int*)d_in[1];
  const float* att = (const float*)d_in[2];
  float*       outg = (float*)d_out;
  const size_t xt_bytes = (size_t)NHEAD * DIM * NNODE * 2;   // 8 MB
  const size_t ab_bytes = (size_t)NNODE * 128 * 4;           // 2 MB
  if (ws_size >= xt_bytes + ab_bytes) {
    unsigned short* xT    = (unsigned short*)d_ws;
    unsigned int*   abits = (unsigned int*)((char*)d_ws + xt_bytes);
    prep_xT<<<dim3(1024), dim3(256), 0, stream>>>(xg, xT);
    prep_adj<<<dim3(4096), dim3(256), 0, stream>>>(adj, abits);
    gat_fused_v2<<<dim3(256), dim3(NTH), 0, stream>>>(xT, abits, att, outg);
  } else {
    gat_fused<<<dim3(256), dim3(512), 0, stream>>>(xg, adj, att, outg);
  }
}

// Round 3
// 124.037 us; speedup vs baseline: 1.4621x; 1.0969x over previous
//
#include <hip/hip_runtime.h>

#define NHEAD 4
#define NNODE 4096
#define DIM 256
#define ROWS 32
#define CT 64
#define NT (NNODE / CT)
#define NEGV (-9e15f)

typedef float        f32x4  __attribute__((ext_vector_type(4)));
typedef int          i32x4  __attribute__((ext_vector_type(4)));
typedef unsigned int u32x2  __attribute__((ext_vector_type(2)));
typedef unsigned int u32x4  __attribute__((ext_vector_type(4)));
typedef short        bf16x8 __attribute__((ext_vector_type(8)));
typedef float        f32x16 __attribute__((ext_vector_type(16)));

__device__ __forceinline__ unsigned int f2bf(float f) {
  unsigned int u = __float_as_uint(f);
  u += 0x7fffu + ((u >> 16) & 1u);   // RNE to bf16
  return u >> 16;
}

// ---- pre-pass 1: xF = x re-laid-out in exact MFMA B-fragment order (8 MB) ----
// chunk (h, it, ks, lhi, d) of 8 bf16: x[h][it*64+ks*16+lhi*8+j][d], j=0..7
__global__ __launch_bounds__(256) void prep_xF(const float* __restrict__ xg,
                                               unsigned short* __restrict__ xF) {
  __shared__ unsigned short tile[64 * 260];   // [n][d], stride 260 to spread banks
  const int b = blockIdx.x;        // 256 blocks = 4 h x 64 it
  const int h = b >> 6;
  const int it = b & 63;
  const int t = threadIdx.x;
  const int n = t >> 2;
  const int dsg = (t & 3) << 6;
  const float* src = xg + ((size_t)h * NNODE + (it << 6) + n) * DIM + dsg;
#pragma unroll
  for (int j = 0; j < 16; ++j) {
    const f32x4 v = *(const f32x4*)(src + 4 * j);
    u32x2 w;
    w[0] = f2bf(v[0]) | (f2bf(v[1]) << 16);
    w[1] = f2bf(v[2]) | (f2bf(v[3]) << 16);
    *(u32x2*)&tile[n * 260 + dsg + 4 * j] = w;
  }
  __syncthreads();
  const int d = t;
  unsigned short* ob = xF + ((size_t)((h << 6) + it) * 2048 + d) * 8;
#pragma unroll
  for (int ks = 0; ks < 4; ++ks)
#pragma unroll
    for (int lh = 0; lh < 2; ++lh) {
      bf16x8 val;
#pragma unroll
      for (int j = 0; j < 8; ++j) val[j] = (short)tile[(ks * 16 + lh * 8 + j) * 260 + d];
      *(bf16x8*)(ob + (size_t)(ks * 2 + lh) * 256 * 8) = val;
    }
}

// ---- pre-pass 2: adjacency -> bitmask (2 MB, L2-resident) ----
__global__ __launch_bounds__(256) void prep_adj(const int* __restrict__ adj,
                                                unsigned int* __restrict__ bits) {
  const int row = blockIdx.x;
  const int t = threadIdx.x;
  const int lane = t & 63, wv = t >> 6;
#pragma unroll
  for (int rep = 0; rep < 16; ++rep) {
    const int c = (rep << 8) + t;
    const unsigned long long m = __ballot(adj[(size_t)row * NNODE + c] > 0);
    if (lane == 0) {
      bits[row * 128 + (rep << 3) + (wv << 1)]     = (unsigned int)m;
      bits[row * 128 + (rep << 3) + (wv << 1) + 1] = (unsigned int)(m >> 32);
    }
  }
}

// ---- main: shift-free softmax (P=exp(s), masked->0), P@X via MFMA ----
// 8 waves/block, 32 rows/block, grid 512 (2 blocks/CU). Per iter: compute P
// tile -> LDS (dbuf, 1 barrier), MFMA with B-frags loaded straight from L2.
// Denominator = per-thread register partial sum, reduced once at the end.
__global__ __launch_bounds__(512, 4) void gat_v3(
    const unsigned short* __restrict__ xF, const unsigned int* __restrict__ abits,
    const float* __restrict__ att, float* __restrict__ outg) {
  __shared__ unsigned short p_lds[2][ROWS * CT];   // 8 KB
  __shared__ float l_lds[ROWS];

  const int t = threadIdx.x;
  const int lane = t & 63;
  const int flat = blockIdx.x;
  const int xcd = flat & 7;                 // round-robin XCD dispatch
  const int h   = xcd >> 1;                 // head pinned to an XCD pair
  const int rb  = ((xcd & 1) << 6) | (flat >> 3);   // 0..127
  const int r0  = rb * ROWS;

  // score mapping: 16 threads/row, 4 cols each
  const int sr  = t >> 4;                   // 0..31
  const int c4  = (t & 15) << 2;            // 0..60
  const float* attb = att + ((size_t)h * NNODE + r0 + sr) * NNODE + c4;
  const unsigned int* ab = abits + (size_t)(r0 + sr) * 128 + (c4 >> 5);
  const int bsh = c4 & 31;

  // mfma mapping: wave -> 32-wide d slice
  const int wv   = t >> 6;
  const int d0   = wv << 5;
  const int lhi  = lane >> 5;
  const int lcol = lane & 31;
  const int axor = (lcol & 7) << 3;
  // B-frag base: xF chunk ((h*64+it)*8 + ks*2+lhi)*256 + d, 8 bf16 each
  const unsigned short* xfb = xF + (size_t)h * NT * 16384 + ((lhi << 8) + d0 + lcol) * 8;

  f32x16 acc = {0.f};
  float psum = 0.f;

  // prologue: att/bits 2-deep, B-frags 1-deep
  f32x4 a0 = __builtin_nontemporal_load((const f32x4*)attb);
  f32x4 a1 = __builtin_nontemporal_load((const f32x4*)(attb + CT));
  unsigned int w0 = ab[0], w1 = ab[2];
  bf16x8 xf0 = *(const bf16x8*)(xfb);
  bf16x8 xf1 = *(const bf16x8*)(xfb + 4096);
  bf16x8 xf2 = *(const bf16x8*)(xfb + 8192);
  bf16x8 xf3 = *(const bf16x8*)(xfb + 12288);

  int buf = 0;
  for (int it = 0; it < NT; ++it) {
    // issue att/bits prefetch for it+2
    const int it2 = (it + 2) & (NT - 1);
    const f32x4 a2 = __builtin_nontemporal_load((const f32x4*)(attb + it2 * CT));
    const unsigned int w2 = ab[it2 << 1];

    // P = exp(lrelu masked) — no max tracking (softmax is shift-invariant)
    float e0, e1, e2, e3;
    {
      float s0 = a0[0], s1 = a0[1], s2 = a0[2], s3 = a0[3];
      s0 = fmaxf(s0, 0.2f * s0); s1 = fmaxf(s1, 0.2f * s1);
      s2 = fmaxf(s2, 0.2f * s2); s3 = fmaxf(s3, 0.2f * s3);
      s0 = ((w0 >> (bsh + 0)) & 1u) ? s0 : NEGV;
      s1 = ((w0 >> (bsh + 1)) & 1u) ? s1 : NEGV;
      s2 = ((w0 >> (bsh + 2)) & 1u) ? s2 : NEGV;
      s3 = ((w0 >> (bsh + 3)) & 1u) ? s3 : NEGV;
      e0 = __expf(s0); e1 = __expf(s1); e2 = __expf(s2); e3 = __expf(s3);
      psum += (e0 + e1) + (e2 + e3);
    }
    u32x2 pk;
    pk[0] = f2bf(e0) | (f2bf(e1) << 16);
    pk[1] = f2bf(e2) | (f2bf(e3) << 16);
    *(u32x2*)&p_lds[buf][sr * CT + (c4 ^ ((sr & 7) << 3))] = pk;

    // prefetch next B-frags (L2 hits; land during barrier+MFMA)
    const int itn = (it + 1) & (NT - 1);
    const unsigned short* xfi = xfb + (size_t)itn * 16384;
    const bf16x8 nx0 = *(const bf16x8*)(xfi);
    const bf16x8 nx1 = *(const bf16x8*)(xfi + 4096);
    const bf16x8 nx2 = *(const bf16x8*)(xfi + 8192);
    const bf16x8 nx3 = *(const bf16x8*)(xfi + 12288);

    __syncthreads();   // one barrier per iteration (dbuf P)

    const unsigned short* pr = &p_lds[buf][lcol * CT];
    const int mkb = lhi << 3;
    const bf16x8 A0 = *(const bf16x8*)&pr[(mkb +  0) ^ axor];
    const bf16x8 A1 = *(const bf16x8*)&pr[(mkb + 16) ^ axor];
    const bf16x8 A2 = *(const bf16x8*)&pr[(mkb + 32) ^ axor];
    const bf16x8 A3 = *(const bf16x8*)&pr[(mkb + 48) ^ axor];
    acc = __builtin_amdgcn_mfma_f32_32x32x16_bf16(A0, xf0, acc, 0, 0, 0);
    acc = __builtin_amdgcn_mfma_f32_32x32x16_bf16(A1, xf1, acc, 0, 0, 0);
    acc = __builtin_amdgcn_mfma_f32_32x32x16_bf16(A2, xf2, acc, 0, 0, 0);
    acc = __builtin_amdgcn_mfma_f32_32x32x16_bf16(A3, xf3, acc, 0, 0, 0);

    a0 = a1; a1 = a2; w0 = w1; w1 = w2;
    xf0 = nx0; xf1 = nx1; xf2 = nx2; xf3 = nx3;
    buf ^= 1;
  }

  // ---- epilogue: reduce denominator once, normalize, store ----
  float l = psum;
  l += __shfl_xor(l, 1);
  l += __shfl_xor(l, 2);
  l += __shfl_xor(l, 4);
  l += __shfl_xor(l, 8);
  if ((t & 15) == 0) l_lds[sr] = l;
  __syncthreads();
  float* outb = outg + ((size_t)h * NNODE + r0) * DIM + d0 + lcol;
#pragma unroll
  for (int q = 0; q < 4; ++q) {
    const f32x4 lv = *(const f32x4*)&l_lds[q * 8 + lhi * 4];
    const int rbase = q * 8 + lhi * 4;   // C/D row = (reg&3)+8*(reg>>2)+4*(lane>>5)
#pragma unroll
    for (int i = 0; i < 4; ++i)
      __builtin_nontemporal_store(acc[q * 4 + i] / lv[i], outb + (size_t)(rbase + i) * DIM);
  }
}

// ---------- R1 kernel kept as fallback when ws is too small ----------
__global__ __launch_bounds__(512, 4) void gat_fused(
    const float* __restrict__ xg, const int* __restrict__ adj,
    const float* __restrict__ att, float* __restrict__ outg) {
  __shared__ __align__(16) unsigned short p_l[64 * 64];
  __shared__ __align__(16) unsigned short xT_l[DIM * 64];
  __shared__ __align__(16) float fac_l[64];
  __shared__ __align__(16) float ll_l[64];
  const int t = threadIdx.x;
  const int lane = t & 63;
  const int flat = blockIdx.x;
  const int xcd  = flat & 7;
  const int h    = xcd >> 1;
  const int rb   = ((xcd & 1) << 5) | (flat >> 3);
  const int r0   = rb * 64;
  const int srow = t >> 3;
  const int sm0  = (t & 7) << 3;
  const float* attb = att + ((size_t)h * NNODE + (r0 + srow)) * NNODE + sm0;
  const int*   adjb = adj + (size_t)(r0 + srow) * NNODE + sm0;
  const int xm0 = (t >> 5) << 2;
  const int xd0 = (t & 31) << 2;
  const float* xb_h = xg + (size_t)h * NNODE * DIM;
  const int wv   = t >> 6;
  const int d0   = wv << 5;
  const int lhi  = lane >> 5;
  const int lcol = lane & 31;
  f32x16 acc0 = {0.f};
  f32x16 acc1 = {0.f};
  float m_run = -__builtin_inff();
  float l_run = 0.f;
  for (int it = 0; it < 64; ++it) {
    const int c0 = it * 64;
    {
      const f32x4 A0 = __builtin_nontemporal_load((const f32x4*)(attb + c0));
      const f32x4 A1 = __builtin_nontemporal_load((const f32x4*)(attb + c0) + 1);
      const i32x4 j0 = *((const i32x4*)(adjb + c0));
      const i32x4 j1 = *((const i32x4*)(adjb + c0) + 1);
      float sv[8];
      int   av[8];
#pragma unroll
      for (int k = 0; k < 4; ++k) { sv[k] = A0[k]; sv[4 + k] = A1[k]; av[k] = j0[k]; av[4 + k] = j1[k]; }
#pragma unroll
      for (int k = 0; k < 8; ++k) {
        float s = sv[k];
        s = s > 0.f ? s : 0.2f * s;
        sv[k] = (av[k] > 0) ? s : NEGV;
      }
      float tmax = sv[0];
#pragma unroll
      for (int k = 1; k < 8; ++k) tmax = fmaxf(tmax, sv[k]);
      tmax = fmaxf(tmax, __shfl_xor(tmax, 1));
      tmax = fmaxf(tmax, __shfl_xor(tmax, 2));
      tmax = fmaxf(tmax, __shfl_xor(tmax, 4));
      const float m_new = fmaxf(m_run, tmax);
      float ps = 0.f;
#pragma unroll
      for (int k = 0; k < 8; ++k) { sv[k] = __expf(sv[k] - m_new); ps += sv[k]; }
      ps += __shfl_xor(ps, 1);
      ps += __shfl_xor(ps, 2);
      ps += __shfl_xor(ps, 4);
      const float fac = __expf(m_run - m_new);
      l_run = l_run * fac + ps;
      m_run = m_new;
      if ((t & 7) == 0) fac_l[srow] = fac;
      u32x4 pk;
      pk[0] = f2bf(sv[0]) | (f2bf(sv[1]) << 16);
      pk[1] = f2bf(sv[2]) | (f2bf(sv[3]) << 16);
      pk[2] = f2bf(sv[4]) | (f2bf(sv[5]) << 16);
      pk[3] = f2bf(sv[6]) | (f2bf(sv[7]) << 16);
      *(u32x4*)&p_l[srow * 64 + (sm0 ^ ((srow & 7) << 3))] = pk;
    }
    {
      const float* xb = xb_h + (size_t)(c0 + xm0) * DIM;
#pragma unroll
      for (int hh2 = 0; hh2 < 2; ++hh2) {
        const int dbase = xd0 + hh2 * 128;
        const f32x4 r0v = *(const f32x4*)(xb + dbase);
        const f32x4 r1v = *(const f32x4*)(xb + DIM + dbase);
        const f32x4 r2v = *(const f32x4*)(xb + 2 * DIM + dbase);
        const f32x4 r3v = *(const f32x4*)(xb + 3 * DIM + dbase);
#pragma unroll
        for (int j = 0; j < 4; ++j) {
          const int d = dbase + j;
          u32x2 wds;
          wds[0] = f2bf(r0v[j]) | (f2bf(r1v[j]) << 16);
          wds[1] = f2bf(r2v[j]) | (f2bf(r3v[j]) << 16);
          *(u32x2*)&xT_l[d * 64 + (xm0 ^ (((d >> 2) & 7) << 3))] = wds;
        }
      }
    }
    __syncthreads();
    {
#pragma unroll
      for (int q = 0; q < 4; ++q) {
        const f32x4 fa = *(const f32x4*)&fac_l[q * 8 + lhi * 4];
        const f32x4 fb = *(const f32x4*)&fac_l[32 + q * 8 + lhi * 4];
#pragma unroll
        for (int i = 0; i < 4; ++i) { acc0[q * 4 + i] *= fa[i]; acc1[q * 4 + i] *= fb[i]; }
      }
#pragma unroll
      for (int ks = 0; ks < 4; ++ks) {
        const int mk = ks * 16 + lhi * 8;
        const bf16x8 afA = *(const bf16x8*)&p_l[lcol * 64 + (mk ^ ((lcol & 7) << 3))];
        const bf16x8 afB = *(const bf16x8*)&p_l[(32 + lcol) * 64 + (mk ^ ((lcol & 7) << 3))];
        const int dd = d0 + lcol;
        const bf16x8 bfr = *(const bf16x8*)&xT_l[dd * 64 + (mk ^ (((dd >> 2) & 7) << 3))];
        acc0 = __builtin_amdgcn_mfma_f32_32x32x16_bf16(afA, bfr, acc0, 0, 0, 0);
        acc1 = __builtin_amdgcn_mfma_f32_32x32x16_bf16(afB, bfr, acc1, 0, 0, 0);
      }
    }
    __syncthreads();
  }
  if ((t & 7) == 0) ll_l[srow] = l_run;
  __syncthreads();
  float* outb = outg + (size_t)h * NNODE * DIM + (size_t)r0 * DIM + d0 + lcol;
#pragma unroll
  for (int q = 0; q < 4; ++q) {
    const f32x4 la = *(const f32x4*)&ll_l[q * 8 + lhi * 4];
    const f32x4 lb = *(const f32x4*)&ll_l[32 + q * 8 + lhi * 4];
    const int rbase = q * 8 + lhi * 4;
#pragma unroll
    for (int i = 0; i < 4; ++i) {
      __builtin_nontemporal_store(acc0[q * 4 + i] / la[i], outb + (size_t)(rbase + i) * DIM);
      __builtin_nontemporal_store(acc1[q * 4 + i] / lb[i], outb + (size_t)(32 + rbase + i) * DIM);
    }
  }
}

extern "C" void kernel_launch(void* const* d_in, const int* in_sizes, int n_in,
                              void* d_out, int out_size, void* d_ws, size_t ws_size,
                              hipStream_t stream) {
  const float* xg  = (const float*)d_in[0];
  const int*   adj = (const int*)d_in[1];
  const float* att = (const float*)d_in[2];
  float*       outg = (float*)d_out;
  const size_t xf_bytes = (size_t)NHEAD * DIM * NNODE * 2;   // 8 MB
  const size_t ab_bytes = (size_t)NNODE * 128 * 4;           // 2 MB
  if (ws_size >= xf_bytes + ab_bytes) {
    unsigned short* xF    = (unsigned short*)d_ws;
    unsigned int*   abits = (unsigned int*)((char*)d_ws + xf_bytes);
    prep_xF<<<dim3(256), dim3(256), 0, stream>>>(xg, xF);
    prep_adj<<<dim3(4096), dim3(256), 0, stream>>>(adj, abits);
    gat_v3<<<dim3(512), dim3(512), 0, stream>>>(xF, abits, att, outg);
  } else {
    gat_fused<<<dim3(256), dim3(512), 0, stream>>>(xg, adj, att, outg);
  }
}

// Round 4
// 123.973 us; speedup vs baseline: 1.4629x; 1.0005x over previous
//
#include <hip/hip_runtime.h>

#define NHEAD 4
#define NNODE 4096
#define DIM 256
#define ROWS 32
#define CT 64
#define NT (NNODE / CT)
#define NEGV (-9e15f)

typedef float        f32x4  __attribute__((ext_vector_type(4)));
typedef int          i32x4  __attribute__((ext_vector_type(4)));
typedef unsigned int u32x2  __attribute__((ext_vector_type(2)));
typedef unsigned int u32x4  __attribute__((ext_vector_type(4)));
typedef short        bf16x8 __attribute__((ext_vector_type(8)));
typedef float        f32x16 __attribute__((ext_vector_type(16)));

__device__ __forceinline__ unsigned int f2bf(float f) {
  unsigned int u = __float_as_uint(f);
  u += 0x7fffu + ((u >> 16) & 1u);   // RNE to bf16
  return u >> 16;
}

// ---- pre-pass 1: xF = x re-laid-out in exact MFMA B-fragment order (8 MB) ----
// chunk (h, it, ks, lhi, d) of 8 bf16: x[h][it*64+ks*16+lhi*8+j][d], j=0..7
__global__ __launch_bounds__(256) void prep_xF(const float* __restrict__ xg,
                                               unsigned short* __restrict__ xF) {
  __shared__ unsigned short tile[64 * 260];   // [n][d], stride 260 to spread banks
  const int b = blockIdx.x;        // 256 blocks = 4 h x 64 it
  const int h = b >> 6;
  const int it = b & 63;
  const int t = threadIdx.x;
  const int n = t >> 2;
  const int dsg = (t & 3) << 6;
  const float* src = xg + ((size_t)h * NNODE + (it << 6) + n) * DIM + dsg;
#pragma unroll
  for (int j = 0; j < 16; ++j) {
    const f32x4 v = *(const f32x4*)(src + 4 * j);
    u32x2 w;
    w[0] = f2bf(v[0]) | (f2bf(v[1]) << 16);
    w[1] = f2bf(v[2]) | (f2bf(v[3]) << 16);
    *(u32x2*)&tile[n * 260 + dsg + 4 * j] = w;
  }
  __syncthreads();
  const int d = t;
  unsigned short* ob = xF + ((size_t)((h << 6) + it) * 2048 + d) * 8;
#pragma unroll
  for (int ks = 0; ks < 4; ++ks)
#pragma unroll
    for (int lh = 0; lh < 2; ++lh) {
      bf16x8 val;
#pragma unroll
      for (int j = 0; j < 8; ++j) val[j] = (short)tile[(ks * 16 + lh * 8 + j) * 260 + d];
      *(bf16x8*)(ob + (size_t)(ks * 2 + lh) * 256 * 8) = val;
    }
}

// ---- pre-pass 2: adjacency -> bitmask (2 MB, L2-resident) ----
__global__ __launch_bounds__(256) void prep_adj(const int* __restrict__ adj,
                                                unsigned int* __restrict__ bits) {
  const int row = blockIdx.x;
  const int t = threadIdx.x;
  const int lane = t & 63, wv = t >> 6;
#pragma unroll
  for (int rep = 0; rep < 16; ++rep) {
    const int c = (rep << 8) + t;
    const unsigned long long m = __ballot(adj[(size_t)row * NNODE + c] > 0);
    if (lane == 0) {
      bits[row * 128 + (rep << 3) + (wv << 1)]     = (unsigned int)m;
      bits[row * 128 + (rep << 3) + (wv << 1) + 1] = (unsigned int)(m >> 32);
    }
  }
}

// ---- main: shift-free softmax (P=exp(s), masked->0), P@X via MFMA ----
// 8 waves/block, 32 rows/block, grid 512 (2 blocks/CU). Per iter: compute P
// tile -> LDS (dbuf), raw s_barrier with lgkmcnt-only drain (att/xF register
// prefetches stay in flight ACROSS the barrier -> HBM latency hidden), MFMA
// with B-frags loaded straight from L2. Denominator reduced once at the end.
__global__ __launch_bounds__(512, 4) void gat_v3(
    const unsigned short* __restrict__ xF, const unsigned int* __restrict__ abits,
    const float* __restrict__ att, float* __restrict__ outg) {
  __shared__ unsigned short p_lds[2][ROWS * CT];   // 8 KB
  __shared__ float l_lds[ROWS];

  const int t = threadIdx.x;
  const int lane = t & 63;
  const int flat = blockIdx.x;
  const int xcd = flat & 7;                 // round-robin XCD dispatch
  const int h   = xcd >> 1;                 // head pinned to an XCD pair
  const int rb  = ((xcd & 1) << 6) | (flat >> 3);   // 0..127
  const int r0  = rb * ROWS;

  // score mapping: 16 threads/row, 4 cols each
  const int sr  = t >> 4;                   // 0..31
  const int c4  = (t & 15) << 2;            // 0..60
  const float* attb = att + ((size_t)h * NNODE + r0 + sr) * NNODE + c4;
  const unsigned int* ab = abits + (size_t)(r0 + sr) * 128 + (c4 >> 5);
  const int bsh = c4 & 31;

  // mfma mapping: wave -> 32-wide d slice
  const int wv   = t >> 6;
  const int d0   = wv << 5;
  const int lhi  = lane >> 5;
  const int lcol = lane & 31;
  const int axor = (lcol & 7) << 3;
  // B-frag base: xF chunk ((h*64+it)*8 + ks*2+lhi)*256 + d, 8 bf16 each
  const unsigned short* xfb = xF + (size_t)h * NT * 16384 + ((lhi << 8) + d0 + lcol) * 8;

  f32x16 acc = {0.f};
  float psum = 0.f;

  // prologue: att/bits 2-deep, B-frags 1-deep
  f32x4 a0 = __builtin_nontemporal_load((const f32x4*)attb);
  f32x4 a1 = __builtin_nontemporal_load((const f32x4*)(attb + CT));
  unsigned int w0 = ab[0], w1 = ab[2];
  bf16x8 xf0 = *(const bf16x8*)(xfb);
  bf16x8 xf1 = *(const bf16x8*)(xfb + 4096);
  bf16x8 xf2 = *(const bf16x8*)(xfb + 8192);
  bf16x8 xf3 = *(const bf16x8*)(xfb + 12288);

  int buf = 0;
  for (int it = 0; it < NT; ++it) {
    // issue att/bits prefetch for it+2
    const int it2 = (it + 2) & (NT - 1);
    const f32x4 a2 = __builtin_nontemporal_load((const f32x4*)(attb + it2 * CT));
    const unsigned int w2 = ab[it2 << 1];

    // P = exp(lrelu masked) — no max tracking (softmax is shift-invariant)
    float e0, e1, e2, e3;
    {
      float s0 = a0[0], s1 = a0[1], s2 = a0[2], s3 = a0[3];
      s0 = fmaxf(s0, 0.2f * s0); s1 = fmaxf(s1, 0.2f * s1);
      s2 = fmaxf(s2, 0.2f * s2); s3 = fmaxf(s3, 0.2f * s3);
      s0 = ((w0 >> (bsh + 0)) & 1u) ? s0 : NEGV;
      s1 = ((w0 >> (bsh + 1)) & 1u) ? s1 : NEGV;
      s2 = ((w0 >> (bsh + 2)) & 1u) ? s2 : NEGV;
      s3 = ((w0 >> (bsh + 3)) & 1u) ? s3 : NEGV;
      e0 = __expf(s0); e1 = __expf(s1); e2 = __expf(s2); e3 = __expf(s3);
      psum += (e0 + e1) + (e2 + e3);
    }
    u32x2 pk;
    pk[0] = f2bf(e0) | (f2bf(e1) << 16);
    pk[1] = f2bf(e2) | (f2bf(e3) << 16);
    *(u32x2*)&p_lds[buf][sr * CT + (c4 ^ ((sr & 7) << 3))] = pk;

    // prefetch next B-frags (L2 hits; stay in flight across the barrier)
    const int itn = (it + 1) & (NT - 1);
    const unsigned short* xfi = xfb + (size_t)itn * 16384;
    const bf16x8 nx0 = *(const bf16x8*)(xfi);
    const bf16x8 nx1 = *(const bf16x8*)(xfi + 4096);
    const bf16x8 nx2 = *(const bf16x8*)(xfi + 8192);
    const bf16x8 nx3 = *(const bf16x8*)(xfi + 12288);

    // raw barrier with lgkmcnt-only drain: own P ds_write must land (lgkmcnt),
    // but global prefetches (vmcnt) stay outstanding across the barrier.
    asm volatile("s_waitcnt lgkmcnt(0)" ::: "memory");
    __builtin_amdgcn_s_barrier();

    const unsigned short* pr = &p_lds[buf][lcol * CT];
    const int mkb = lhi << 3;
    const bf16x8 A0 = *(const bf16x8*)&pr[(mkb +  0) ^ axor];
    const bf16x8 A1 = *(const bf16x8*)&pr[(mkb + 16) ^ axor];
    const bf16x8 A2 = *(const bf16x8*)&pr[(mkb + 32) ^ axor];
    const bf16x8 A3 = *(const bf16x8*)&pr[(mkb + 48) ^ axor];
    acc = __builtin_amdgcn_mfma_f32_32x32x16_bf16(A0, xf0, acc, 0, 0, 0);
    acc = __builtin_amdgcn_mfma_f32_32x32x16_bf16(A1, xf1, acc, 0, 0, 0);
    acc = __builtin_amdgcn_mfma_f32_32x32x16_bf16(A2, xf2, acc, 0, 0, 0);
    acc = __builtin_amdgcn_mfma_f32_32x32x16_bf16(A3, xf3, acc, 0, 0, 0);

    a0 = a1; a1 = a2; w0 = w1; w1 = w2;
    xf0 = nx0; xf1 = nx1; xf2 = nx2; xf3 = nx3;
    buf ^= 1;
  }

  // ---- epilogue: reduce denominator once, normalize, store ----
  float l = psum;
  l += __shfl_xor(l, 1);
  l += __shfl_xor(l, 2);
  l += __shfl_xor(l, 4);
  l += __shfl_xor(l, 8);
  if ((t & 15) == 0) l_lds[sr] = l;
  __syncthreads();
  float* outb = outg + ((size_t)h * NNODE + r0) * DIM + d0 + lcol;
#pragma unroll
  for (int q = 0; q < 4; ++q) {
    const f32x4 lv = *(const f32x4*)&l_lds[q * 8 + lhi * 4];
    const int rbase = q * 8 + lhi * 4;   // C/D row = (reg&3)+8*(reg>>2)+4*(lane>>5)
#pragma unroll
    for (int i = 0; i < 4; ++i)
      __builtin_nontemporal_store(acc[q * 4 + i] / lv[i], outb + (size_t)(rbase + i) * DIM);
  }
}

// ---------- R1 kernel kept as fallback when ws is too small ----------
__global__ __launch_bounds__(512, 4) void gat_fused(
    const float* __restrict__ xg, const int* __restrict__ adj,
    const float* __restrict__ att, float* __restrict__ outg) {
  __shared__ __align__(16) unsigned short p_l[64 * 64];
  __shared__ __align__(16) unsigned short xT_l[DIM * 64];
  __shared__ __align__(16) float fac_l[64];
  __shared__ __align__(16) float ll_l[64];
  const int t = threadIdx.x;
  const int lane = t & 63;
  const int flat = blockIdx.x;
  const int xcd  = flat & 7;
  const int h    = xcd >> 1;
  const int rb   = ((xcd & 1) << 5) | (flat >> 3);
  const int r0   = rb * 64;
  const int srow = t >> 3;
  const int sm0  = (t & 7) << 3;
  const float* attb = att + ((size_t)h * NNODE + (r0 + srow)) * NNODE + sm0;
  const int*   adjb = adj + (size_t)(r0 + srow) * NNODE + sm0;
  const int xm0 = (t >> 5) << 2;
  const int xd0 = (t & 31) << 2;
  const float* xb_h = xg + (size_t)h * NNODE * DIM;
  const int wv   = t >> 6;
  const int d0   = wv << 5;
  const int lhi  = lane >> 5;
  const int lcol = lane & 31;
  f32x16 acc0 = {0.f};
  f32x16 acc1 = {0.f};
  float m_run = -__builtin_inff();
  float l_run = 0.f;
  for (int it = 0; it < 64; ++it) {
    const int c0 = it * 64;
    {
      const f32x4 A0 = __builtin_nontemporal_load((const f32x4*)(attb + c0));
      const f32x4 A1 = __builtin_nontemporal_load((const f32x4*)(attb + c0) + 1);
      const i32x4 j0 = *((const i32x4*)(adjb + c0));
      const i32x4 j1 = *((const i32x4*)(adjb + c0) + 1);
      float sv[8];
      int   av[8];
#pragma unroll
      for (int k = 0; k < 4; ++k) { sv[k] = A0[k]; sv[4 + k] = A1[k]; av[k] = j0[k]; av[4 + k] = j1[k]; }
#pragma unroll
      for (int k = 0; k < 8; ++k) {
        float s = sv[k];
        s = s > 0.f ? s : 0.2f * s;
        sv[k] = (av[k] > 0) ? s : NEGV;
      }
      float tmax = sv[0];
#pragma unroll
      for (int k = 1; k < 8; ++k) tmax = fmaxf(tmax, sv[k]);
      tmax = fmaxf(tmax, __shfl_xor(tmax, 1));
      tmax = fmaxf(tmax, __shfl_xor(tmax, 2));
      tmax = fmaxf(tmax, __shfl_xor(tmax, 4));
      const float m_new = fmaxf(m_run, tmax);
      float ps = 0.f;
#pragma unroll
      for (int k = 0; k < 8; ++k) { sv[k] = __expf(sv[k] - m_new); ps += sv[k]; }
      ps += __shfl_xor(ps, 1);
      ps += __shfl_xor(ps, 2);
      ps += __shfl_xor(ps, 4);
      const float fac = __expf(m_run - m_new);
      l_run = l_run * fac + ps;
      m_run = m_new;
      if ((t & 7) == 0) fac_l[srow] = fac;
      u32x4 pk;
      pk[0] = f2bf(sv[0]) | (f2bf(sv[1]) << 16);
      pk[1] = f2bf(sv[2]) | (f2bf(sv[3]) << 16);
      pk[2] = f2bf(sv[4]) | (f2bf(sv[5]) << 16);
      pk[3] = f2bf(sv[6]) | (f2bf(sv[7]) << 16);
      *(u32x4*)&p_l[srow * 64 + (sm0 ^ ((srow & 7) << 3))] = pk;
    }
    {
      const float* xb = xb_h + (size_t)(c0 + xm0) * DIM;
#pragma unroll
      for (int hh2 = 0; hh2 < 2; ++hh2) {
        const int dbase = xd0 + hh2 * 128;
        const f32x4 r0v = *(const f32x4*)(xb + dbase);
        const f32x4 r1v = *(const f32x4*)(xb + DIM + dbase);
        const f32x4 r2v = *(const f32x4*)(xb + 2 * DIM + dbase);
        const f32x4 r3v = *(const f32x4*)(xb + 3 * DIM + dbase);
#pragma unroll
        for (int j = 0; j < 4; ++j) {
          const int d = dbase + j;
          u32x2 wds;
          wds[0] = f2bf(r0v[j]) | (f2bf(r1v[j]) << 16);
          wds[1] = f2bf(r2v[j]) | (f2bf(r3v[j]) << 16);
          *(u32x2*)&xT_l[d * 64 + (xm0 ^ (((d >> 2) & 7) << 3))] = wds;
        }
      }
    }
    __syncthreads();
    {
#pragma unroll
      for (int q = 0; q < 4; ++q) {
        const f32x4 fa = *(const f32x4*)&fac_l[q * 8 + lhi * 4];
        const f32x4 fb = *(const f32x4*)&fac_l[32 + q * 8 + lhi * 4];
#pragma unroll
        for (int i = 0; i < 4; ++i) { acc0[q * 4 + i] *= fa[i]; acc1[q * 4 + i] *= fb[i]; }
      }
#pragma unroll
      for (int ks = 0; ks < 4; ++ks) {
        const int mk = ks * 16 + lhi * 8;
        const bf16x8 afA = *(const bf16x8*)&p_l[lcol * 64 + (mk ^ ((lcol & 7) << 3))];
        const bf16x8 afB = *(const bf16x8*)&p_l[(32 + lcol) * 64 + (mk ^ ((lcol & 7) << 3))];
        const int dd = d0 + lcol;
        const bf16x8 bfr = *(const bf16x8*)&xT_l[dd * 64 + (mk ^ (((dd >> 2) & 7) << 3))];
        acc0 = __builtin_amdgcn_mfma_f32_32x32x16_bf16(afA, bfr, acc0, 0, 0, 0);
        acc1 = __builtin_amdgcn_mfma_f32_32x32x16_bf16(afB, bfr, acc1, 0, 0, 0);
      }
    }
    __syncthreads();
  }
  if ((t & 7) == 0) ll_l[srow] = l_run;
  __syncthreads();
  float* outb = outg + (size_t)h * NNODE * DIM + (size_t)r0 * DIM + d0 + lcol;
#pragma unroll
  for (int q = 0; q < 4; ++q) {
    const f32x4 la = *(const f32x4*)&ll_l[q * 8 + lhi * 4];
    const f32x4 lb = *(const f32x4*)&ll_l[32 + q * 8 + lhi * 4];
    const int rbase = q * 8 + lhi * 4;
#pragma unroll
    for (int i = 0; i < 4; ++i) {
      __builtin_nontemporal_store(acc0[q * 4 + i] / la[i], outb + (size_t)(rbase + i) * DIM);
      __builtin_nontemporal_store(acc1[q * 4 + i] / lb[i], outb + (size_t)(32 + rbase + i) * DIM);
    }
  }
}

extern "C" void kernel_launch(void* const* d_in, const int* in_sizes, int n_in,
                              void* d_out, int out_size, void* d_ws, size_t ws_size,
                              hipStream_t stream) {
  const float* xg  = (const float*)d_in[0];
  const int*   adj = (const int*)d_in[1];
  const float* att = (const float*)d_in[2];
  float*       outg = (float*)d_out;
  const size_t xf_bytes = (size_t)NHEAD * DIM * NNODE * 2;   // 8 MB
  const size_t ab_bytes = (size_t)NNODE * 128 * 4;           // 2 MB
  if (ws_size >= xf_bytes + ab_bytes) {
    unsigned short* xF    = (unsigned short*)d_ws;
    unsigned int*   abits = (unsigned int*)((char*)d_ws + xf_bytes);
    prep_xF<<<dim3(256), dim3(256), 0, stream>>>(xg, xF);
    prep_adj<<<dim3(4096), dim3(256), 0, stream>>>(adj, abits);
    gat_v3<<<dim3(512), dim3(512), 0, stream>>>(xF, abits, att, outg);
  } else {
    gat_fused<<<dim3(256), dim3(512), 0, stream>>>(xg, adj, att, outg);
  }
}